// Round 8
// baseline (2005.449 us; speedup 1.0000x reference)
//
#include <hip/hip_runtime.h>
#include <math.h>

#define DD 768
#define FF 3072
#define SS 512
#define BB 16
#define NH 12
#define DH 64
#define NL 4
#define MM (BB*SS)   // 8192

typedef __attribute__((ext_vector_type(8))) short short8;
typedef __attribute__((ext_vector_type(4))) float f32x4;

__device__ __forceinline__ unsigned short f2bf(float f) {
  unsigned u = __float_as_uint(f);
  return (unsigned short)((u + 0x7FFFu + ((u >> 16) & 1u)) >> 16);
}
__device__ __forceinline__ float bf2f(unsigned short s) {
  return __uint_as_float(((unsigned)s) << 16);
}

#define GLOAD_LDS(g, l) \
  __builtin_amdgcn_global_load_lds((const __attribute__((address_space(1))) void*)(g), \
                                   (__attribute__((address_space(3))) void*)(l), 16, 0, 0)

// ---------------- copy / convert ----------------
__global__ __launch_bounds__(256) void copy_f32_k(const float* __restrict__ in,
                                                  float* __restrict__ out, int n) {
  for (int i = blockIdx.x*256 + threadIdx.x; i < n; i += gridDim.x*256)
    out[i] = in[i];
}
__global__ __launch_bounds__(256) void cvt_dual_k(const float* __restrict__ in,
                                                  float* __restrict__ outf,
                                                  unsigned short* __restrict__ outb, int n) {
  for (int i = blockIdx.x*256 + threadIdx.x; i < n; i += gridDim.x*256) {
    float v = in[i]; outf[i] = v; outb[i] = f2bf(v);
  }
}

// fp32 [K,N] -> bf16 [N,K] tiled transpose-convert
__global__ __launch_bounds__(256) void tcvt_k(const float* __restrict__ src,
                                              unsigned short* __restrict__ dst,
                                              int K, int N) {
  __shared__ float t[32][33];
  const int n0 = blockIdx.x*32, k0 = blockIdx.y*32;
  const int tx = threadIdx.x & 31, ty = threadIdx.x >> 5;
#pragma unroll
  for (int i = 0; i < 32; i += 8)
    t[ty+i][tx] = src[(size_t)(k0+ty+i)*N + n0+tx];
  __syncthreads();
#pragma unroll
  for (int i = 0; i < 32; i += 8)
    dst[(size_t)(n0+ty+i)*K + k0+tx] = f2bf(t[tx][ty+i]);
}

// concat 4x768 biases -> 3072
__global__ __launch_bounds__(256) void bcat_k(const float* __restrict__ a,
                                              const float* __restrict__ b,
                                              const float* __restrict__ c,
                                              const float* __restrict__ d,
                                              float* __restrict__ out) {
  int i = blockIdx.x*256 + threadIdx.x;   // 0..3071
  int w = i / 768;
  const float* s = (w == 0) ? a : (w == 1) ? b : (w == 2) ? c : d;
  out[i] = s[i - w*768];
}

// ---------------- MFMA bf16 GEMM: C[M,N] = A[M,K] @ Bw[N,K]^T + bias ----------------
// EPI: 0 bias; 1 bias+resid(fp32); 2 bias+exact gelu.  OBF: 1 -> bf16 out, 0 -> fp32 out.
template<int EPI, int OBF>
__global__ __launch_bounds__(256) void mgemm_k(
    const unsigned short* __restrict__ A,   // [M,K] bf16
    const unsigned short* __restrict__ Bw,  // [N,K] bf16 (pre-transposed weights)
    const float* __restrict__ bias,         // [N] fp32
    const float* __restrict__ resid,        // [M,N] fp32 (EPI==1)
    void* __restrict__ Cout, int M, int N, int K)
{
  __shared__ __align__(16) unsigned short As[128*32];
  __shared__ __align__(16) unsigned short Bs[128*32];
  const int bm = blockIdx.y*128, bn = blockIdx.x*128;
  const int tid = threadIdx.x;
  const int wave = tid >> 6, lane = tid & 63;
  const int wm = (wave >> 1)*64, wn = (wave & 1)*64;

  f32x4 acc[4][4] = {};

  const unsigned short* Ag = A  + (size_t)(bm + wave*32 + (lane>>2))*K + (lane&3)*8;
  const unsigned short* Bg = Bw + (size_t)(bn + wave*32 + (lane>>2))*K + (lane&3)*8;
  unsigned short* AsW = As + wave*32*32;
  unsigned short* BsW = Bs + wave*32*32;

  for (int k0 = 0; k0 < K; k0 += 32) {
    GLOAD_LDS(Ag,                AsW);
    GLOAD_LDS(Ag + 16*(size_t)K, AsW + 16*32);
    GLOAD_LDS(Bg,                BsW);
    GLOAD_LDS(Bg + 16*(size_t)K, BsW + 16*32);
    Ag += 32; Bg += 32;
    __syncthreads();
    short8 af[4], bfr[4];
#pragma unroll
    for (int i = 0; i < 4; ++i) {
      af[i]  = *(const short8*)&As[(wm + i*16 + (lane & 15))*32 + (lane >> 4)*8];
      bfr[i] = *(const short8*)&Bs[(wn + i*16 + (lane & 15))*32 + (lane >> 4)*8];
    }
#pragma unroll
    for (int i = 0; i < 4; ++i)
#pragma unroll
      for (int j = 0; j < 4; ++j)
        acc[i][j] = __builtin_amdgcn_mfma_f32_16x16x32_bf16(af[i], bfr[j], acc[i][j], 0, 0, 0);
    __syncthreads();
  }

  const int col0 = bn + wn + (lane & 15);
  const int row0 = bm + wm + (lane >> 4)*4;
#pragma unroll
  for (int i = 0; i < 4; ++i) {
#pragma unroll
    for (int j = 0; j < 4; ++j) {
      const int n = col0 + j*16;
      const float bv = bias[n];
#pragma unroll
      for (int r = 0; r < 4; ++r) {
        const int m = row0 + i*16 + r;
        float v = acc[i][j][r] + bv;
        if (EPI == 1) v += resid[(size_t)m*N + n];
        if (EPI == 2) v = 0.5f*v*(1.0f + erff(v*0.70710678118654752f));
        if (OBF) ((unsigned short*)Cout)[(size_t)m*N + n] = f2bf(v);
        else     ((float*)Cout)[(size_t)m*N + n] = v;
      }
    }
  }
}

// ---------------- per-(b,h,s) reciprocal context-vector L2 norm ----------------
__global__ __launch_bounds__(64) void cnorm_k(const unsigned short* __restrict__ c,
                                              float* __restrict__ rn) {
  int idx = blockIdx.x;          // (b*NH + h)*SS + s
  int s  = idx % SS;
  int bh = idx / SS;
  int h  = bh % NH;
  int b  = bh / NH;
  int tid = threadIdx.x;
  float v = bf2f(c[((size_t)(b*SS + s))*FF + h*DH + tid]);
  float ss = v*v;
#pragma unroll
  for (int off = 32; off; off >>= 1) ss += __shfl_xor(ss, off, 64);
  if (tid == 0) rn[idx] = rsqrtf(ss);   // store 1/||c||
}

// ---------------- V transpose: [b,s][h,d] (pitch FF) -> VT[bh][d][s] ----------------
__global__ __launch_bounds__(256) void vtrans_k(const unsigned short* __restrict__ v,
                                                unsigned short* __restrict__ VT) {
  __shared__ unsigned short t[64][72];
  const int s0 = blockIdx.x*64;
  const int h  = blockIdx.y;
  const int b  = blockIdx.z;
  const size_t base = (size_t)(b*SS)*FF + h*DH;
  const int row = threadIdx.x >> 2, seg = threadIdx.x & 3;
  const unsigned short* vg = v + base + (size_t)(s0+row)*FF + seg*16;
  *(uint4*)&t[row][seg*16]     = *(const uint4*)vg;
  *(uint4*)&t[row][seg*16 + 8] = *(const uint4*)(vg + 8);
  __syncthreads();
  unsigned short o[16];
#pragma unroll
  for (int u = 0; u < 16; ++u) o[u] = t[seg*16 + u][row];
  unsigned short* og = VT + ((size_t)(b*NH + h)*DH + row)*SS + s0 + seg*16;
  *(uint4*)og       = *(const uint4*)&o[0];
  *(uint4*)(og + 8) = *(const uint4*)&o[8];
}

// ---------------- barrier-free MFMA dual-branch flash attention ----------------
// Block: (64 q-rows, h, b) = 4 independent waves, 16 q-rows each. All MFMA
// operand frags are 16B-contiguous global reads (L1/L2 broadcast); LDS holds
// only the per-wave P round-trip. Branch1 (bounded scores in [0,3]) uses a
// fixed max=3 (no reduce, no rescale); branch2 keeps online max.
__global__ __launch_bounds__(256) void attn4_k(
    const unsigned short* __restrict__ q, const unsigned short* __restrict__ k,
    const unsigned short* __restrict__ c, const float* __restrict__ rn,
    const unsigned short* __restrict__ VT, unsigned short* __restrict__ ctxO)
{
  const int l0 = blockIdx.x * 64;
  const int h  = blockIdx.y;
  const int b  = blockIdx.z;
  const int tid = threadIdx.x;
  const int wave = tid >> 6, lane = tid & 63;
  const int wm = wave * 16;
  const int fr = lane & 15;     // frag row (A/B) / col (C,D)
  const int fg = lane >> 4;     // k-group (A/B) / row-quad (C,D)
  const int bh = b*NH + h;
  const size_t base   = (size_t)(b*SS)*FF + h*DH;
  const size_t vtbase = (size_t)bh*DH*SS;

  __shared__ unsigned short P1s[4][16*72];
  __shared__ unsigned short P2s[4][16*72];
  unsigned short* P1w = P1s[wave];
  unsigned short* P2w = P2s[wave];

  // loop-invariant A-frags straight from global (16B contiguous)
  const unsigned short* qrow = q + base + (size_t)(l0 + wm + fr)*FF + fg*8;
  const unsigned short* crow = c + base + (size_t)(l0 + wm + fr)*FF + fg*8;
  const short8 aQ0 = *(const short8*)qrow;
  const short8 aQ1 = *(const short8*)(qrow + 32);
  const short8 aC0 = *(const short8*)crow;
  const short8 aC1 = *(const short8*)(crow + 32);

  float rnl[4];
#pragma unroll
  for (int reg = 0; reg < 4; ++reg)
    rnl[reg] = rn[(size_t)bh*SS + l0 + wm + fg*4 + reg];

  float rm2[4], rs2[4], rs1[4];
#pragma unroll
  for (int r = 0; r < 4; ++r) { rm2[r] = -1e30f; rs2[r] = 0.f; rs1[r] = 0.f; }
  f32x4 oc1[4] = {}, oc2[4] = {};

#pragma unroll 1
  for (int it = 0; it < 8; ++it) {
    const int r0 = it*64;

    // ---- dual scores via MFMA, B-frags direct from global ----
    f32x4 s1a[4] = {}, s2a[4] = {};
    float rnr[4];
#pragma unroll
    for (int nt = 0; nt < 4; ++nt) {
      const size_t roff = (size_t)(r0 + nt*16 + fr)*FF + fg*8;
      const unsigned short* kr = k + base + roff;
      const unsigned short* cr = c + base + roff;
      const short8 bK0 = *(const short8*)kr;
      const short8 bK1 = *(const short8*)(kr + 32);
      const short8 bC0 = *(const short8*)cr;
      const short8 bC1 = *(const short8*)(cr + 32);
      s2a[nt] = __builtin_amdgcn_mfma_f32_16x16x32_bf16(aQ0, bK0, s2a[nt], 0,0,0);
      s2a[nt] = __builtin_amdgcn_mfma_f32_16x16x32_bf16(aQ1, bK1, s2a[nt], 0,0,0);
      s1a[nt] = __builtin_amdgcn_mfma_f32_16x16x32_bf16(aC0, bC0, s1a[nt], 0,0,0);
      s1a[nt] = __builtin_amdgcn_mfma_f32_16x16x32_bf16(aC1, bC1, s1a[nt], 0,0,0);
      rnr[nt] = rn[(size_t)bh*SS + r0 + nt*16 + fr];
    }

    // ---- branch scores; D-layout: row = wm+fg*4+reg, col = nt*16+fr ----
    float sv1[4][4], sv2[4][4];   // [reg][nt]
#pragma unroll
    for (int nt = 0; nt < 4; ++nt)
#pragma unroll
      for (int reg = 0; reg < 4; ++reg) {
        const int ql = wm + fg*4 + reg;
        const int rr = nt*16 + fr;
        sv2[reg][nt] = s2a[nt][reg] * 0.125f;
        sv1[reg][nt] = 1.0f - s1a[nt][reg]*rnl[reg]*rnr[nt]
                     + ((l0+ql) == (r0+rr) ? 1.0f : 0.0f);
      }

    // ---- branch 1: fixed max = 3 (scores bounded), per-lane partial sum ----
#pragma unroll
    for (int reg = 0; reg < 4; ++reg) {
      const int prow = (fg*4 + reg)*72;
#pragma unroll
      for (int nt = 0; nt < 4; ++nt) {
        const float x1 = __expf(sv1[reg][nt] - 3.0f);
        P1w[prow + nt*16 + fr] = f2bf(x1);
        rs1[reg] += x1;
      }
    }
    // ---- branch 2: online max, per-lane partial sum ----
#pragma unroll
    for (int reg = 0; reg < 4; ++reg) {
      float t2 = fmaxf(fmaxf(sv2[reg][0], sv2[reg][1]), fmaxf(sv2[reg][2], sv2[reg][3]));
#pragma unroll
      for (int off = 1; off < 16; off <<= 1)
        t2 = fmaxf(t2, __shfl_xor(t2, off, 64));
      const float mn2 = fmaxf(rm2[reg], t2);
      const float f2  = __expf(rm2[reg] - mn2);
      rm2[reg] = mn2;
      const int prow = (fg*4 + reg)*72;
      float e2 = 0.f;
#pragma unroll
      for (int nt = 0; nt < 4; ++nt) {
        const float x2 = __expf(sv2[reg][nt] - mn2);
        P2w[prow + nt*16 + fr] = f2bf(x2);
        e2 += x2;
      }
      rs2[reg] = rs2[reg]*f2 + e2;
      oc2[0][reg] *= f2; oc2[1][reg] *= f2; oc2[2][reg] *= f2; oc2[3][reg] *= f2;
    }

    // ---- PV via MFMA: A = P rows (same-wave LDS, in-order DS pipe), B = VT ----
    const short8 p10 = *(const short8*)&P1w[fr*72 + fg*8];
    const short8 p11 = *(const short8*)&P1w[fr*72 + fg*8 + 32];
    const short8 p20 = *(const short8*)&P2w[fr*72 + fg*8];
    const short8 p21 = *(const short8*)&P2w[fr*72 + fg*8 + 32];
#pragma unroll
    for (int nt = 0; nt < 4; ++nt) {
      const unsigned short* vtr = VT + (vtbase + (size_t)(nt*16 + fr)*SS) + r0 + fg*8;
      const short8 bv0 = *(const short8*)vtr;
      const short8 bv1 = *(const short8*)(vtr + 32);
      oc1[nt] = __builtin_amdgcn_mfma_f32_16x16x32_bf16(p10, bv0, oc1[nt], 0,0,0);
      oc1[nt] = __builtin_amdgcn_mfma_f32_16x16x32_bf16(p11, bv1, oc1[nt], 0,0,0);
      oc2[nt] = __builtin_amdgcn_mfma_f32_16x16x32_bf16(p20, bv0, oc2[nt], 0,0,0);
      oc2[nt] = __builtin_amdgcn_mfma_f32_16x16x32_bf16(p21, bv1, oc2[nt], 0,0,0);
    }
  }

  // ---- final cross-lane sum reduce (within 16-lane fr group) + blend + store ----
#pragma unroll
  for (int reg = 0; reg < 4; ++reg) {
    float t1 = rs1[reg], t2 = rs2[reg];
#pragma unroll
    for (int off = 1; off < 16; off <<= 1) {
      t1 += __shfl_xor(t1, off, 64);
      t2 += __shfl_xor(t2, off, 64);
    }
    const float i1 = 0.5f / t1;
    const float i2 = 0.5f / t2;
    const int Mrow = b*SS + l0 + wm + fg*4 + reg;
    unsigned short* og = ctxO + (size_t)Mrow*DD + h*DH;
#pragma unroll
    for (int nt = 0; nt < 4; ++nt)
      og[nt*16 + fr] = f2bf(oc1[nt][reg]*i1 + oc2[nt][reg]*i2);
  }
}

// ---------------- in-place row LayerNorm over D=768, + bf16 mirror ----------------
__global__ __launch_bounds__(256) void ln_k(float* __restrict__ x,
                                            const float* __restrict__ g,
                                            const float* __restrict__ b,
                                            unsigned short* __restrict__ xb) {
  __shared__ float xs[DD];
  __shared__ float red[4];
  const int tid = threadIdx.x;
  float* xr = x + (size_t)blockIdx.x * DD;
  unsigned short* xbr = xb + (size_t)blockIdx.x * DD;
  float s = 0.f;
  for (int d = tid; d < DD; d += 256) { float v = xr[d]; xs[d] = v; s += v; }
#pragma unroll
  for (int off = 32; off; off >>= 1) s += __shfl_xor(s, off, 64);
  if ((tid & 63) == 0) red[tid >> 6] = s;
  __syncthreads();
  float mu = (red[0]+red[1]+red[2]+red[3]) * (1.f/DD);
  __syncthreads();
  float s2 = 0.f;
  for (int d = tid; d < DD; d += 256) { float t = xs[d]-mu; s2 += t*t; }
#pragma unroll
  for (int off = 32; off; off >>= 1) s2 += __shfl_xor(s2, off, 64);
  if ((tid & 63) == 0) red[tid >> 6] = s2;
  __syncthreads();
  float var = (red[0]+red[1]+red[2]+red[3]) * (1.f/DD);
  float rstd = rsqrtf(var + 1e-12f);
  for (int d = tid; d < DD; d += 256) {
    float o = (xs[d]-mu)*rstd*g[d] + b[d];
    xr[d] = o;
    xbr[d] = f2bf(o);
  }
}

// ---------------- launcher ----------------
extern "C" void kernel_launch(void* const* d_in, const int* in_sizes, int n_in,
                              void* d_out, int out_size, void* d_ws, size_t ws_size,
                              hipStream_t stream) {
  const float* hs  = (const float*)d_in[0];
  const float* Wq  = (const float*)d_in[1];  const float* bq  = (const float*)d_in[2];
  const float* Wk  = (const float*)d_in[3];  const float* bk  = (const float*)d_in[4];
  const float* Wv  = (const float*)d_in[5];  const float* bv  = (const float*)d_in[6];
  const float* Wc  = (const float*)d_in[7];  const float* bc  = (const float*)d_in[8];
  const float* Wo  = (const float*)d_in[9];  const float* bo  = (const float*)d_in[10];
  const float* g1  = (const float*)d_in[11]; const float* b1  = (const float*)d_in[12];
  const float* Wi  = (const float*)d_in[13]; const float* bi  = (const float*)d_in[14];
  const float* Wo2 = (const float*)d_in[15]; const float* bo2 = (const float*)d_in[16];
  const float* g2  = (const float*)d_in[17]; const float* b2  = (const float*)d_in[18];

  const size_t XN  = (size_t)MM * DD;       // 6,291,456
  const size_t HN  = (size_t)MM * FF;       // 25,165,824
  const int    nBH = BB*NH*SS;              // 98304
  const size_t WTN = 7667712;               // per-layer transposed weights (elems)

  char* p = (char*)d_ws;
  float*          x      = (float*)p;           p += XN*4;
  float*          attnf  = (float*)p;           p += XN*4;
  unsigned short* qkvc16 = (unsigned short*)p;  p += HN*2;   // also hb16 (aliased)
  unsigned short* xb16   = (unsigned short*)p;  p += XN*2;
  unsigned short* ctx16  = (unsigned short*)p;  p += XN*2;
  unsigned short* attn16 = (unsigned short*)p;  p += XN*2;
  unsigned short* vt16   = (unsigned short*)p;  p += XN*2;   // V^T [bh][d][s]
  unsigned short* WT     = (unsigned short*)p;  p += WTN*2;
  float*          bqkvc  = (float*)p;           p += 3072*4;
  float*          cnb    = (float*)p;           p += (size_t)nBH*4;
  const size_t need = (size_t)(p - (char*)d_ws);
  if (ws_size < need) return;

  unsigned short* WqkvcT = WT;                    // [3072][768]
  unsigned short* WoT    = WT + 2359296;          // [768][768]
  unsigned short* WiT    = WT + 2949120;          // [3072][768]
  unsigned short* Wo2T   = WT + 5308416;          // [768][3072]
  unsigned short* hb16   = qkvc16;                // FFN intermediate aliases QKVC

  cvt_dual_k<<<4096, 256, 0, stream>>>(hs, x, xb16, (int)XN);

  dim3 gGQ(FF/128, MM/128);   // 24 x 64  (QKVC, Wi)
  dim3 gGD(DD/128, MM/128);   // 6  x 64  (Wo, Wo2)
  dim3 gA(SS/64, NH, BB);     // 8 x 12 x 16 = 1536
  dim3 tDD(DD/32, DD/32);     // 24 x 24
  dim3 tDF(FF/32, DD/32);     // 96 x 24  (src [D,F])
  dim3 tFD(DD/32, FF/32);     // 24 x 96  (src [F,D])

  for (int i = 0; i < NL; ++i) {
    const size_t wD = (size_t)i*DD*DD, wF = (size_t)i*DD*FF;
    tcvt_k<<<tDD, 256, 0, stream>>>(Wq + wD, WqkvcT,            DD, DD);
    tcvt_k<<<tDD, 256, 0, stream>>>(Wk + wD, WqkvcT +  768*768, DD, DD);
    tcvt_k<<<tDD, 256, 0, stream>>>(Wv + wD, WqkvcT + 1536*768, DD, DD);
    tcvt_k<<<tDD, 256, 0, stream>>>(Wc + wD, WqkvcT + 2304*768, DD, DD);
    tcvt_k<<<tDD, 256, 0, stream>>>(Wo + wD, WoT,  DD, DD);
    tcvt_k<<<tDF, 256, 0, stream>>>(Wi + wF, WiT,  DD, FF);
    tcvt_k<<<tFD, 256, 0, stream>>>(Wo2 + wF, Wo2T, FF, DD);
    bcat_k<<<12, 256, 0, stream>>>(bq + (size_t)i*DD, bk + (size_t)i*DD,
                                   bv + (size_t)i*DD, bc + (size_t)i*DD, bqkvc);

    // fused QKVC projection: [8192,768] @ [768,3072] -> bf16 [8192,3072]
    mgemm_k<0,1><<<gGQ, 256, 0, stream>>>(xb16, WqkvcT, bqkvc, nullptr, qkvc16, MM, FF, DD);

    cnorm_k<<<nBH, 64, 0, stream>>>(qkvc16 + 2304, cnb);
    vtrans_k<<<gA, 256, 0, stream>>>(qkvc16 + 1536, vt16);
    attn4_k<<<gA, 256, 0, stream>>>(qkvc16, qkvc16 + 768, qkvc16 + 2304,
                                    cnb, vt16, ctx16);

    // attn_out = LN1(ctx @ Wo + bo + x)
    mgemm_k<1,0><<<gGD, 256, 0, stream>>>(ctx16, WoT, bo + (size_t)i*DD, x, attnf, MM, DD, DD);
    ln_k<<<MM, 256, 0, stream>>>(attnf, g1 + (size_t)i*DD, b1 + (size_t)i*DD, attn16);

    // h = gelu(attn @ Wi + bi) -> bf16 (overwrites dead qkvc16)
    mgemm_k<2,1><<<gGQ, 256, 0, stream>>>(attn16, WiT, bi + (size_t)i*FF, nullptr, hb16, MM, FF, DD);
    // x = LN2(h @ Wo2 + bo2 + attn)
    mgemm_k<1,0><<<gGD, 256, 0, stream>>>(hb16, Wo2T, bo2 + (size_t)i*DD, attnf, x, MM, DD, FF);
    ln_k<<<MM, 256, 0, stream>>>(x, g2 + (size_t)i*DD, b2 + (size_t)i*DD, xb16);
  }

  copy_f32_k<<<4096, 256, 0, stream>>>(x, (float*)d_out, (int)XN);
}

// Round 9
// 1856.173 us; speedup vs baseline: 1.0804x; 1.0804x over previous
//
#include <hip/hip_runtime.h>
#include <math.h>

#define DD 768
#define FF 3072
#define SS 512
#define BB 16
#define NH 12
#define DH 64
#define NL 4
#define MM (BB*SS)   // 8192

typedef __attribute__((ext_vector_type(8))) short short8;
typedef __attribute__((ext_vector_type(4))) float f32x4;

__device__ __forceinline__ unsigned short f2bf(float f) {
  unsigned u = __float_as_uint(f);
  return (unsigned short)((u + 0x7FFFu + ((u >> 16) & 1u)) >> 16);
}
__device__ __forceinline__ float bf2f(unsigned short s) {
  return __uint_as_float(((unsigned)s) << 16);
}

#define GLOAD_LDS(g, l) \
  __builtin_amdgcn_global_load_lds((const __attribute__((address_space(1))) void*)(g), \
                                   (__attribute__((address_space(3))) void*)(l), 16, 0, 0)

// ---------------- convert ----------------
__global__ __launch_bounds__(256) void cvt_dual_k(const float* __restrict__ in,
                                                  float* __restrict__ outf,
                                                  unsigned short* __restrict__ outb, int n) {
  for (int i = blockIdx.x*256 + threadIdx.x; i < n; i += gridDim.x*256) {
    float v = in[i]; outf[i] = v; outb[i] = f2bf(v);
  }
}

// fp32 [K,N] -> bf16 [N,K] tiled transpose-convert
__global__ __launch_bounds__(256) void tcvt_k(const float* __restrict__ src,
                                              unsigned short* __restrict__ dst,
                                              int K, int N) {
  __shared__ float t[32][33];
  const int n0 = blockIdx.x*32, k0 = blockIdx.y*32;
  const int tx = threadIdx.x & 31, ty = threadIdx.x >> 5;
#pragma unroll
  for (int i = 0; i < 32; i += 8)
    t[ty+i][tx] = src[(size_t)(k0+ty+i)*N + n0+tx];
  __syncthreads();
#pragma unroll
  for (int i = 0; i < 32; i += 8)
    dst[(size_t)(n0+ty+i)*K + k0+tx] = f2bf(t[tx][ty+i]);
}

// concat 4x768 biases -> 3072
__global__ __launch_bounds__(256) void bcat_k(const float* __restrict__ a,
                                              const float* __restrict__ b,
                                              const float* __restrict__ c,
                                              const float* __restrict__ d,
                                              float* __restrict__ out) {
  int i = blockIdx.x*256 + threadIdx.x;   // 0..3071
  int w = i / 768;
  const float* s = (w == 0) ? a : (w == 1) ? b : (w == 2) ? c : d;
  out[i] = s[i - w*768];
}

// ---------------- MFMA bf16 GEMM: C[M,N] = A[M,K] @ Bw[N,K]^T + bias ----------------
// EPI: 0 bias; 1 bias+resid(fp32); 2 bias+exact gelu.  OBF: 1 -> bf16 out, 0 -> fp32 out.
template<int EPI, int OBF>
__global__ __launch_bounds__(256) void mgemm_k(
    const unsigned short* __restrict__ A,   // [M,K] bf16
    const unsigned short* __restrict__ Bw,  // [N,K] bf16 (pre-transposed weights)
    const float* __restrict__ bias,         // [N] fp32
    const float* __restrict__ resid,        // [M,N] fp32 (EPI==1)
    void* __restrict__ Cout, int M, int N, int K)
{
  __shared__ __align__(16) unsigned short As[128*32];
  __shared__ __align__(16) unsigned short Bs[128*32];
  const int bm = blockIdx.y*128, bn = blockIdx.x*128;
  const int tid = threadIdx.x;
  const int wave = tid >> 6, lane = tid & 63;
  const int wm = (wave >> 1)*64, wn = (wave & 1)*64;

  f32x4 acc[4][4] = {};

  const unsigned short* Ag = A  + (size_t)(bm + wave*32 + (lane>>2))*K + (lane&3)*8;
  const unsigned short* Bg = Bw + (size_t)(bn + wave*32 + (lane>>2))*K + (lane&3)*8;
  unsigned short* AsW = As + wave*32*32;
  unsigned short* BsW = Bs + wave*32*32;

  for (int k0 = 0; k0 < K; k0 += 32) {
    GLOAD_LDS(Ag,                AsW);
    GLOAD_LDS(Ag + 16*(size_t)K, AsW + 16*32);
    GLOAD_LDS(Bg,                BsW);
    GLOAD_LDS(Bg + 16*(size_t)K, BsW + 16*32);
    Ag += 32; Bg += 32;
    __syncthreads();
    short8 af[4], bfr[4];
#pragma unroll
    for (int i = 0; i < 4; ++i) {
      af[i]  = *(const short8*)&As[(wm + i*16 + (lane & 15))*32 + (lane >> 4)*8];
      bfr[i] = *(const short8*)&Bs[(wn + i*16 + (lane & 15))*32 + (lane >> 4)*8];
    }
#pragma unroll
    for (int i = 0; i < 4; ++i)
#pragma unroll
      for (int j = 0; j < 4; ++j)
        acc[i][j] = __builtin_amdgcn_mfma_f32_16x16x32_bf16(af[i], bfr[j], acc[i][j], 0, 0, 0);
    __syncthreads();
  }

  const int col0 = bn + wn + (lane & 15);
  const int row0 = bm + wm + (lane >> 4)*4;
#pragma unroll
  for (int i = 0; i < 4; ++i) {
#pragma unroll
    for (int j = 0; j < 4; ++j) {
      const int n = col0 + j*16;
      const float bv = bias[n];
#pragma unroll
      for (int r = 0; r < 4; ++r) {
        const int m = row0 + i*16 + r;
        float v = acc[i][j][r] + bv;
        if (EPI == 1) v += resid[(size_t)m*N + n];
        if (EPI == 2) v = 0.5f*v*(1.0f + erff(v*0.70710678118654752f));
        if (OBF) ((unsigned short*)Cout)[(size_t)m*N + n] = f2bf(v);
        else     ((float*)Cout)[(size_t)m*N + n] = v;
      }
    }
  }
}

// ---------------- per-(b,h,s) reciprocal context-vector L2 norm ----------------
// 256 threads = 4 waves, one row per wave.
__global__ __launch_bounds__(256) void cnorm_k(const unsigned short* __restrict__ c,
                                               float* __restrict__ rn) {
  int idx = blockIdx.x*4 + (threadIdx.x >> 6);   // (b*NH + h)*SS + s
  int lane = threadIdx.x & 63;
  int s  = idx % SS;
  int bh = idx / SS;
  int h  = bh % NH;
  int b  = bh / NH;
  float v = bf2f(c[((size_t)(b*SS + s))*FF + h*DH + lane]);
  float ss = v*v;
#pragma unroll
  for (int off = 32; off; off >>= 1) ss += __shfl_xor(ss, off, 64);
  if (lane == 0) rn[idx] = rsqrtf(ss);   // store 1/||c||
}

// ---------------- V transpose: [b,s][h,d] (pitch FF) -> VT[bh][d][s] ----------------
__global__ __launch_bounds__(256) void vtrans_k(const unsigned short* __restrict__ v,
                                                unsigned short* __restrict__ VT) {
  __shared__ unsigned short t[64][72];
  const int s0 = blockIdx.x*64;
  const int h  = blockIdx.y;
  const int b  = blockIdx.z;
  const size_t base = (size_t)(b*SS)*FF + h*DH;
  const int row = threadIdx.x >> 2, seg = threadIdx.x & 3;
  const unsigned short* vg = v + base + (size_t)(s0+row)*FF + seg*16;
  *(uint4*)&t[row][seg*16]     = *(const uint4*)vg;
  *(uint4*)&t[row][seg*16 + 8] = *(const uint4*)(vg + 8);
  __syncthreads();
  unsigned short o[16];
#pragma unroll
  for (int u = 0; u < 16; ++u) o[u] = t[seg*16 + u][row];
  unsigned short* og = VT + ((size_t)(b*NH + h)*DH + row)*SS + s0 + seg*16;
  *(uint4*)og       = *(const uint4*)&o[0];
  *(uint4*)(og + 8) = *(const uint4*)&o[8];
}

// ---------------- pipelined MFMA dual-branch flash attention ----------------
// Block: (64 q-rows, h, b), 4 waves x 16 q-rows. K/C tiles cooperatively staged
// in padded LDS (conflict-free), register-double-buffered: next tile's global
// loads issue at iter top and their latency overlaps the whole iter's compute.
// One barrier per iter. Single P buffer per wave (same-wave DS ordering).
// Branch1 (scores in [0,2]) uses fixed max; branch2 online max.
__global__ __launch_bounds__(256, 3) void attn5_k(
    const unsigned short* __restrict__ q, const unsigned short* __restrict__ k,
    const unsigned short* __restrict__ c, const float* __restrict__ rn,
    const unsigned short* __restrict__ VT, unsigned short* __restrict__ ctxO)
{
  const int l0 = blockIdx.x * 64;
  const int h  = blockIdx.y;
  const int b  = blockIdx.z;
  const int tid = threadIdx.x;
  const int wave = tid >> 6, lane = tid & 63;
  const int wm = wave * 16;
  const int fr = lane & 15;     // frag row (A/B) / col (C,D)
  const int fg = lane >> 4;     // k-group (A/B) / row-quad (C,D)
  const int bh = b*NH + h;
  const size_t base   = (size_t)(b*SS)*FF + h*DH;
  const size_t vtbase = (size_t)bh*DH*SS;

  __shared__ unsigned short Ks [2][64*72];
  __shared__ unsigned short Crs[2][64*72];
  __shared__ unsigned short Ps [4][16*72];
  unsigned short* Pw = Ps[wave];

  // loop-invariant A-frags straight from global (16B contiguous)
  const unsigned short* qrow = q + base + (size_t)(l0 + wm + fr)*FF + fg*8;
  const unsigned short* crow = c + base + (size_t)(l0 + wm + fr)*FF + fg*8;
  const short8 aQ0 = *(const short8*)qrow;
  const short8 aQ1 = *(const short8*)(qrow + 32);
  const short8 aC0 = *(const short8*)crow;
  const short8 aC1 = *(const short8*)(crow + 32);

  float rnl[4];
#pragma unroll
  for (int reg = 0; reg < 4; ++reg)
    rnl[reg] = rn[(size_t)bh*SS + l0 + wm + fg*4 + reg];

  // ---- stage tile 0 (rows 0..63) ----
  const int srow = tid >> 2, sseg = tid & 3;      // 4 threads/row, 32B each
  {
    const unsigned short* kg = k + base + (size_t)srow*FF + sseg*16;
    const unsigned short* cg = c + base + (size_t)srow*FF + sseg*16;
    *(uint4*)&Ks [0][srow*72 + sseg*16]     = *(const uint4*)kg;
    *(uint4*)&Ks [0][srow*72 + sseg*16 + 8] = *(const uint4*)(kg + 8);
    *(uint4*)&Crs[0][srow*72 + sseg*16]     = *(const uint4*)cg;
    *(uint4*)&Crs[0][srow*72 + sseg*16 + 8] = *(const uint4*)(cg + 8);
  }
  __syncthreads();

  float rm2[4], rs2[4], rs1[4];
#pragma unroll
  for (int r = 0; r < 4; ++r) { rm2[r] = -1e30f; rs2[r] = 0.f; rs1[r] = 0.f; }
  f32x4 oc1[4] = {}, oc2[4] = {};

#pragma unroll 1
  for (int it = 0; it < 8; ++it) {
    const int r0 = it*64;
    const int cur = it & 1, nxt = cur ^ 1;

    // ---- prefetch next K/C tile into registers (latency overlaps this iter) ----
    uint4 nk0, nk1, nc0, nc1;
    if (it < 7) {
      const unsigned short* kg = k + base + (size_t)(r0 + 64 + srow)*FF + sseg*16;
      const unsigned short* cg = c + base + (size_t)(r0 + 64 + srow)*FF + sseg*16;
      nk0 = *(const uint4*)kg;  nk1 = *(const uint4*)(kg + 8);
      nc0 = *(const uint4*)cg;  nc1 = *(const uint4*)(cg + 8);
    }

    // ---- prefetch rnr + VT frags (issue early) ----
    float rnr[4];
    short8 bv0[4], bv1[4];
#pragma unroll
    for (int nt = 0; nt < 4; ++nt) {
      rnr[nt] = rn[(size_t)bh*SS + r0 + nt*16 + fr];
      const unsigned short* vtr = VT + vtbase + (size_t)(nt*16 + fr)*SS + r0 + fg*8;
      bv0[nt] = *(const short8*)vtr;
      bv1[nt] = *(const short8*)(vtr + 32);
    }

    // ---- dual scores via MFMA from staged LDS ----
    f32x4 s1a[4] = {}, s2a[4] = {};
#pragma unroll
    for (int nt = 0; nt < 4; ++nt) {
      const short8 bK0 = *(const short8*)&Ks [cur][(nt*16+fr)*72 + fg*8];
      const short8 bK1 = *(const short8*)&Ks [cur][(nt*16+fr)*72 + fg*8 + 32];
      const short8 bC0 = *(const short8*)&Crs[cur][(nt*16+fr)*72 + fg*8];
      const short8 bC1 = *(const short8*)&Crs[cur][(nt*16+fr)*72 + fg*8 + 32];
      s2a[nt] = __builtin_amdgcn_mfma_f32_16x16x32_bf16(aQ0, bK0, s2a[nt], 0,0,0);
      s2a[nt] = __builtin_amdgcn_mfma_f32_16x16x32_bf16(aQ1, bK1, s2a[nt], 0,0,0);
      s1a[nt] = __builtin_amdgcn_mfma_f32_16x16x32_bf16(aC0, bC0, s1a[nt], 0,0,0);
      s1a[nt] = __builtin_amdgcn_mfma_f32_16x16x32_bf16(aC1, bC1, s1a[nt], 0,0,0);
    }

    // ---- branch scores; D-layout: row = wm+fg*4+reg, col = nt*16+fr ----
    float sv1[4][4], sv2[4][4];   // [reg][nt]
#pragma unroll
    for (int nt = 0; nt < 4; ++nt)
#pragma unroll
      for (int reg = 0; reg < 4; ++reg) {
        const int ql = wm + fg*4 + reg;
        const int rr = nt*16 + fr;
        sv2[reg][nt] = s2a[nt][reg] * 0.125f;
        sv1[reg][nt] = 1.0f - s1a[nt][reg]*rnl[reg]*rnr[nt]
                     + ((l0+ql) == (r0+rr) ? 1.0f : 0.0f);
      }

    // ---- branch 1: fixed max (scores bounded in [0,2]), P -> frags -> PV1 ----
#pragma unroll
    for (int reg = 0; reg < 4; ++reg) {
      const int prow = (fg*4 + reg)*72;
#pragma unroll
      for (int nt = 0; nt < 4; ++nt) {
        const float x1 = __expf(sv1[reg][nt] - 3.0f);
        Pw[prow + nt*16 + fr] = f2bf(x1);
        rs1[reg] += x1;
      }
    }
    {
      const short8 p0 = *(const short8*)&Pw[fr*72 + fg*8];
      const short8 p1 = *(const short8*)&Pw[fr*72 + fg*8 + 32];
#pragma unroll
      for (int nt = 0; nt < 4; ++nt) {
        oc1[nt] = __builtin_amdgcn_mfma_f32_16x16x32_bf16(p0, bv0[nt], oc1[nt], 0,0,0);
        oc1[nt] = __builtin_amdgcn_mfma_f32_16x16x32_bf16(p1, bv1[nt], oc1[nt], 0,0,0);
      }
    }

    // ---- branch 2: online max, P (same buffer, WAR via in-order DS) -> PV2 ----
#pragma unroll
    for (int reg = 0; reg < 4; ++reg) {
      float t2 = fmaxf(fmaxf(sv2[reg][0], sv2[reg][1]), fmaxf(sv2[reg][2], sv2[reg][3]));
#pragma unroll
      for (int off = 1; off < 16; off <<= 1)
        t2 = fmaxf(t2, __shfl_xor(t2, off, 64));
      const float mn2 = fmaxf(rm2[reg], t2);
      const float f2  = __expf(rm2[reg] - mn2);
      rm2[reg] = mn2;
      const int prow = (fg*4 + reg)*72;
      float e2 = 0.f;
#pragma unroll
      for (int nt = 0; nt < 4; ++nt) {
        const float x2 = __expf(sv2[reg][nt] - mn2);
        Pw[prow + nt*16 + fr] = f2bf(x2);
        e2 += x2;
      }
      rs2[reg] = rs2[reg]*f2 + e2;
      oc2[0][reg] *= f2; oc2[1][reg] *= f2; oc2[2][reg] *= f2; oc2[3][reg] *= f2;
    }
    {
      const short8 p0 = *(const short8*)&Pw[fr*72 + fg*8];
      const short8 p1 = *(const short8*)&Pw[fr*72 + fg*8 + 32];
#pragma unroll
      for (int nt = 0; nt < 4; ++nt) {
        oc2[nt] = __builtin_amdgcn_mfma_f32_16x16x32_bf16(p0, bv0[nt], oc2[nt], 0,0,0);
        oc2[nt] = __builtin_amdgcn_mfma_f32_16x16x32_bf16(p1, bv1[nt], oc2[nt], 0,0,0);
      }
    }

    // ---- commit prefetched tile to the other LDS buffer ----
    if (it < 7) {
      *(uint4*)&Ks [nxt][srow*72 + sseg*16]     = nk0;
      *(uint4*)&Ks [nxt][srow*72 + sseg*16 + 8] = nk1;
      *(uint4*)&Crs[nxt][srow*72 + sseg*16]     = nc0;
      *(uint4*)&Crs[nxt][srow*72 + sseg*16 + 8] = nc1;
    }
    __syncthreads();
  }

  // ---- final cross-lane sum reduce + blend + store ----
#pragma unroll
  for (int reg = 0; reg < 4; ++reg) {
    float t1 = rs1[reg], t2 = rs2[reg];
#pragma unroll
    for (int off = 1; off < 16; off <<= 1) {
      t1 += __shfl_xor(t1, off, 64);
      t2 += __shfl_xor(t2, off, 64);
    }
    const float i1 = 0.5f / t1;
    const float i2 = 0.5f / t2;
    const int Mrow = b*SS + l0 + wm + fg*4 + reg;
    unsigned short* og = ctxO + (size_t)Mrow*DD + h*DH;
#pragma unroll
    for (int nt = 0; nt < 4; ++nt)
      og[nt*16 + fr] = f2bf(oc1[nt][reg]*i1 + oc2[nt][reg]*i2);
  }
}

// ---------------- row LayerNorm over D=768: in -> (outf fp32, outb bf16) ----------------
__global__ __launch_bounds__(256) void ln_k(const float* __restrict__ in,
                                            const float* __restrict__ g,
                                            const float* __restrict__ b,
                                            float* __restrict__ outf,
                                            unsigned short* __restrict__ outb) {
  __shared__ float xs[DD];
  __shared__ float red[4];
  const int tid = threadIdx.x;
  const float* xr = in + (size_t)blockIdx.x * DD;
  float* xo = outf + (size_t)blockIdx.x * DD;
  unsigned short* xbr = outb + (size_t)blockIdx.x * DD;
  float s = 0.f;
  for (int d = tid; d < DD; d += 256) { float v = xr[d]; xs[d] = v; s += v; }
#pragma unroll
  for (int off = 32; off; off >>= 1) s += __shfl_xor(s, off, 64);
  if ((tid & 63) == 0) red[tid >> 6] = s;
  __syncthreads();
  float mu = (red[0]+red[1]+red[2]+red[3]) * (1.f/DD);
  __syncthreads();
  float s2 = 0.f;
  for (int d = tid; d < DD; d += 256) { float t = xs[d]-mu; s2 += t*t; }
#pragma unroll
  for (int off = 32; off; off >>= 1) s2 += __shfl_xor(s2, off, 64);
  if ((tid & 63) == 0) red[tid >> 6] = s2;
  __syncthreads();
  float var = (red[0]+red[1]+red[2]+red[3]) * (1.f/DD);
  float rstd = rsqrtf(var + 1e-12f);
  for (int d = tid; d < DD; d += 256) {
    float o = (xs[d]-mu)*rstd*g[d] + b[d];
    xo[d] = o;
    xbr[d] = f2bf(o);
  }
}

// ---------------- launcher ----------------
extern "C" void kernel_launch(void* const* d_in, const int* in_sizes, int n_in,
                              void* d_out, int out_size, void* d_ws, size_t ws_size,
                              hipStream_t stream) {
  const float* hs  = (const float*)d_in[0];
  const float* Wq  = (const float*)d_in[1];  const float* bq  = (const float*)d_in[2];
  const float* Wk  = (const float*)d_in[3];  const float* bk  = (const float*)d_in[4];
  const float* Wv  = (const float*)d_in[5];  const float* bv  = (const float*)d_in[6];
  const float* Wc  = (const float*)d_in[7];  const float* bc  = (const float*)d_in[8];
  const float* Wo  = (const float*)d_in[9];  const float* bo  = (const float*)d_in[10];
  const float* g1  = (const float*)d_in[11]; const float* b1  = (const float*)d_in[12];
  const float* Wi  = (const float*)d_in[13]; const float* bi  = (const float*)d_in[14];
  const float* Wo2 = (const float*)d_in[15]; const float* bo2 = (const float*)d_in[16];
  const float* g2  = (const float*)d_in[17]; const float* b2  = (const float*)d_in[18];

  const size_t XN  = (size_t)MM * DD;       // 6,291,456
  const size_t HN  = (size_t)MM * FF;       // 25,165,824
  const int    nBH = BB*NH*SS;              // 98304
  const size_t WTN = 7667712;               // per-layer transposed weights (elems)

  char* p = (char*)d_ws;
  float*          x      = (float*)p;           p += XN*4;
  float*          attnf  = (float*)p;           p += XN*4;
  unsigned short* qkvc16 = (unsigned short*)p;  p += HN*2;   // also hb16 (aliased)
  unsigned short* xb16   = (unsigned short*)p;  p += XN*2;
  unsigned short* ctx16  = (unsigned short*)p;  p += XN*2;
  unsigned short* attn16 = (unsigned short*)p;  p += XN*2;
  unsigned short* vt16   = (unsigned short*)p;  p += XN*2;   // V^T [bh][d][s]
  unsigned short* WT     = (unsigned short*)p;  p += WTN*2;
  float*          bqkvc  = (float*)p;           p += 3072*4;
  float*          cnb    = (float*)p;           p += (size_t)nBH*4;
  const size_t need = (size_t)(p - (char*)d_ws);
  if (ws_size < need) return;

  unsigned short* WqkvcT = WT;                    // [3072][768]
  unsigned short* WoT    = WT + 2359296;          // [768][768]
  unsigned short* WiT    = WT + 2949120;          // [3072][768]
  unsigned short* Wo2T   = WT + 5308416;          // [768][3072]
  unsigned short* hb16   = qkvc16;                // FFN intermediate aliases QKVC

  cvt_dual_k<<<4096, 256, 0, stream>>>(hs, x, xb16, (int)XN);

  dim3 gGQ(FF/128, MM/128);   // 24 x 64  (QKVC, Wi)
  dim3 gGD(DD/128, MM/128);   // 6  x 64  (Wo, Wo2)
  dim3 gA(SS/64, NH, BB);     // 8 x 12 x 16 = 1536
  dim3 tDD(DD/32, DD/32);     // 24 x 24
  dim3 tDF(FF/32, DD/32);     // 96 x 24  (src [D,F])
  dim3 tFD(DD/32, FF/32);     // 24 x 96  (src [F,D])

  for (int i = 0; i < NL; ++i) {
    const size_t wD = (size_t)i*DD*DD, wF = (size_t)i*DD*FF;
    tcvt_k<<<tDD, 256, 0, stream>>>(Wq + wD, WqkvcT,            DD, DD);
    tcvt_k<<<tDD, 256, 0, stream>>>(Wk + wD, WqkvcT +  768*768, DD, DD);
    tcvt_k<<<tDD, 256, 0, stream>>>(Wv + wD, WqkvcT + 1536*768, DD, DD);
    tcvt_k<<<tDD, 256, 0, stream>>>(Wc + wD, WqkvcT + 2304*768, DD, DD);
    tcvt_k<<<tDD, 256, 0, stream>>>(Wo + wD, WoT,  DD, DD);
    tcvt_k<<<tDF, 256, 0, stream>>>(Wi + wF, WiT,  DD, FF);
    tcvt_k<<<tFD, 256, 0, stream>>>(Wo2 + wF, Wo2T, FF, DD);
    bcat_k<<<12, 256, 0, stream>>>(bq + (size_t)i*DD, bk + (size_t)i*DD,
                                   bv + (size_t)i*DD, bc + (size_t)i*DD, bqkvc);

    // fused QKVC projection: [8192,768] @ [768,3072] -> bf16 [8192,3072]
    mgemm_k<0,1><<<gGQ, 256, 0, stream>>>(xb16, WqkvcT, bqkvc, nullptr, qkvc16, MM, FF, DD);

    cnorm_k<<<nBH/4, 256, 0, stream>>>(qkvc16 + 2304, cnb);
    vtrans_k<<<gA, 256, 0, stream>>>(qkvc16 + 1536, vt16);
    attn5_k<<<gA, 256, 0, stream>>>(qkvc16, qkvc16 + 768, qkvc16 + 2304,
                                    cnb, vt16, ctx16);

    // attn_out = LN1(ctx @ Wo + bo + x)
    mgemm_k<1,0><<<gGD, 256, 0, stream>>>(ctx16, WoT, bo + (size_t)i*DD, x, attnf, MM, DD, DD);
    ln_k<<<MM, 256, 0, stream>>>(attnf, g1 + (size_t)i*DD, b1 + (size_t)i*DD, attnf, attn16);

    // h = gelu(attn @ Wi + bi) -> bf16 (overwrites dead qkvc16)
    mgemm_k<2,1><<<gGQ, 256, 0, stream>>>(attn16, WiT, bi + (size_t)i*FF, nullptr, hb16, MM, FF, DD);
    // x = LN2(h @ Wo2 + bo2 + attn); final layer writes fp32 straight to d_out
    mgemm_k<1,0><<<gGD, 256, 0, stream>>>(hb16, Wo2T, bo2 + (size_t)i*DD, attnf, x, MM, DD, FF);
    float* lnout = (i == NL-1) ? (float*)d_out : x;
    ln_k<<<MM, 256, 0, stream>>>(x, g2 + (size_t)i*DD, b2 + (size_t)i*DD, lnout, xb16);
  }
}